// Round 1
// baseline (758.699 us; speedup 1.0000x reference)
//
#include <hip/hip_runtime.h>
#include <math.h>

#define N_NODES 100000
#define N_EDGES 640000

// ---------------- edge prep ----------------

__global__ __launch_bounds__(256) void k_init(int* __restrict__ deg, int* __restrict__ counter, int n) {
  int i = blockIdx.x * 256 + threadIdx.x;
  if (i < n) deg[i] = 1;            // self-loop
  if (i == 0) *counter = 0;
}

__global__ __launch_bounds__(256) void k_count(const int* __restrict__ dst, int* __restrict__ deg, int e) {
  int i = blockIdx.x * 256 + threadIdx.x;
  if (i < e) atomicAdd(&deg[dst[i]], 1);
}

// per-block exclusive scan + atomic base allocation -> CSR row offsets (order across blocks irrelevant)
__global__ __launch_bounds__(256) void k_alloc(const int* __restrict__ deg, int* __restrict__ row_ptr,
                                               int* __restrict__ fillpos, int* __restrict__ col,
                                               float* __restrict__ dinv, int* __restrict__ counter, int n) {
  __shared__ int sdata[256];
  __shared__ int sbase;
  int tid = threadIdx.x;
  int i = blockIdx.x * 256 + tid;
  int d = (i < n) ? deg[i] : 0;
  sdata[tid] = d;
  __syncthreads();
  for (int off = 1; off < 256; off <<= 1) {
    int v = (tid >= off) ? sdata[tid - off] : 0;
    __syncthreads();
    sdata[tid] += v;
    __syncthreads();
  }
  if (tid == 255) sbase = atomicAdd(counter, sdata[255]);
  __syncthreads();
  int base = sbase;
  if (i < n) {
    int rp = base + sdata[tid] - d;   // exclusive prefix
    row_ptr[i] = rp;
    fillpos[i] = rp + 1;              // slot 0 = self-loop
    col[rp] = i;
    dinv[i] = rsqrtf((float)d);
  }
}

__global__ __launch_bounds__(256) void k_fill(const int* __restrict__ src, const int* __restrict__ dst,
                                              int* __restrict__ fillpos, int* __restrict__ col, int e) {
  int i = blockIdx.x * 256 + threadIdx.x;
  if (i < e) {
    int d = dst[i];
    int p = atomicAdd(&fillpos[d], 1);
    col[p] = src[i];
  }
}

// ---------------- dense GEMM: H[r][c] = dinv[r] * sum_k X[r][k] * W[k][c], N=128 ----------------
// 64 rows/block, 256 threads, 4x8 microtile, K staged in chunks of 32.

__global__ __launch_bounds__(256) void k_gemm128(const float* __restrict__ X, const float* __restrict__ W,
                                                 const float* __restrict__ dinv, float* __restrict__ H, int n) {
  __shared__ float sW[32 * 128];   // [kr][c]
  __shared__ float sX[64 * 36];    // [row][kk], pad 36 (16B-aligned rows, 2-way bank alias only)
  int tid = threadIdx.x;
  int row0 = blockIdx.x * 64;
  int g = tid & 15;          // col group
  int rq = tid >> 4;         // row quad
  int c0 = g * 8;

  float acc[4][8];
#pragma unroll
  for (int i = 0; i < 4; ++i)
#pragma unroll
    for (int j = 0; j < 8; ++j) acc[i][j] = 0.f;

  for (int kc = 0; kc < 4; ++kc) {
    int k0 = kc * 32;
    __syncthreads();
    // stage W chunk (32x128 = 1024 float4)
    {
      const float4* W4 = (const float4*)W;
      float4* sW4 = (float4*)sW;
#pragma unroll
      for (int i = 0; i < 4; ++i) {
        int f = tid + i * 256;           // [0,1024): kr = f/32, c4 = f%32
        sW4[f] = W4[(size_t)(k0 + (f >> 5)) * 32 + (f & 31)];
      }
    }
    // stage X chunk (64 rows x 32 k = 512 float4)
    {
      const float4* X4 = (const float4*)X;
#pragma unroll
      for (int i = 0; i < 2; ++i) {
        int f = tid + i * 256;           // [0,512): row = f/8, k4 = f%8
        int row = f >> 3;
        int k4 = f & 7;
        int grow = row0 + row;
        if (grow >= n) grow = n - 1;     // clamp (result unused)
        float4 v = X4[(size_t)grow * 32 + (k0 >> 2) + k4];
        *((float4*)&sX[row * 36 + k4 * 4]) = v;
      }
    }
    __syncthreads();
#pragma unroll
    for (int k = 0; k < 32; ++k) {
      float a[4];
#pragma unroll
      for (int i = 0; i < 4; ++i) a[i] = sX[(rq * 4 + i) * 36 + k];
      float4 w0 = *((const float4*)&sW[k * 128 + c0]);
      float4 w1 = *((const float4*)&sW[k * 128 + c0 + 4]);
      float w[8] = {w0.x, w0.y, w0.z, w0.w, w1.x, w1.y, w1.z, w1.w};
#pragma unroll
      for (int i = 0; i < 4; ++i)
#pragma unroll
        for (int j = 0; j < 8; ++j) acc[i][j] = fmaf(a[i], w[j], acc[i][j]);
    }
  }
#pragma unroll
  for (int i = 0; i < 4; ++i) {
    int row = row0 + rq * 4 + i;
    if (row < n) {
      float di = dinv[row];
      float4 o0 = make_float4(acc[i][0] * di, acc[i][1] * di, acc[i][2] * di, acc[i][3] * di);
      float4 o1 = make_float4(acc[i][4] * di, acc[i][5] * di, acc[i][6] * di, acc[i][7] * di);
      float4* H4 = (float4*)H;
      H4[(size_t)row * 32 + g * 2] = o0;
      H4[(size_t)row * 32 + g * 2 + 1] = o1;
    }
  }
}

// ---------------- dense GEMM, N=40 (layer 4): wave-per-rows, lanes 0..39 = classes ----------------

__global__ __launch_bounds__(256) void k_gemm40(const float* __restrict__ X, const float* __restrict__ W,
                                                const float* __restrict__ dinv, float* __restrict__ H, int n) {
  __shared__ float sW[128 * 40];
  int tid = threadIdx.x;
  {
    const float4* W4 = (const float4*)W;
    float4* sW4 = (float4*)sW;
    for (int f = tid; f < 1280; f += 256) sW4[f] = W4[f];
  }
  __syncthreads();
  int wave = tid >> 6;
  int lane = tid & 63;
  int row_base = (blockIdx.x * 4 + wave) * 8;
  for (int rr = 0; rr < 8; ++rr) {
    int row = row_base + rr;
    if (row >= n) break;
    float acc = 0.f;
    const float* xr = X + (size_t)row * 128;
    if (lane < 40) {
#pragma unroll
      for (int k = 0; k < 128; ++k) acc = fmaf(xr[k], sW[k * 40 + lane], acc);
      H[(size_t)row * 40 + lane] = acc * dinv[row];
    }
  }
}

// ---------------- aggregation F=128: X_out[i] = relu(dinv[i]*sum_{s in N(i)} H[s] + b) ----------------

__global__ __launch_bounds__(256) void k_agg128(const float* __restrict__ H, const int* __restrict__ col,
                                                const int* __restrict__ row_ptr, const int* __restrict__ deg,
                                                const float* __restrict__ dinv, const float* __restrict__ bias,
                                                float* __restrict__ Xout, int n) {
  int node = blockIdx.x * 4 + (threadIdx.x >> 6);
  int lane = threadIdx.x & 63;
  if (node >= n) return;
  const float2* H2 = (const float2*)H;
  int start = row_ptr[node];
  int cnt = deg[node];
  float ax = 0.f, ay = 0.f;
  for (int j = 0; j < cnt; ++j) {
    int c = col[start + j];
    float2 v = H2[(size_t)c * 64 + lane];
    ax += v.x; ay += v.y;
  }
  float di = dinv[node];
  float2 b = ((const float2*)bias)[lane];
  float o0 = fmaf(ax, di, b.x);
  float o1 = fmaf(ay, di, b.y);
  o0 = o0 > 0.f ? o0 : 0.f;
  o1 = o1 > 0.f ? o1 : 0.f;
  ((float2*)Xout)[(size_t)node * 64 + lane] = make_float2(o0, o1);
}

// ---------------- aggregation F=40 + bias + log_softmax fused ----------------

__global__ __launch_bounds__(256) void k_agg40_lsm(const float* __restrict__ H, const int* __restrict__ col,
                                                   const int* __restrict__ row_ptr, const int* __restrict__ deg,
                                                   const float* __restrict__ dinv, const float* __restrict__ bias,
                                                   float* __restrict__ out, int n) {
  int node = blockIdx.x * 4 + (threadIdx.x >> 6);
  int lane = threadIdx.x & 63;
  if (node >= n) return;
  int start = row_ptr[node];
  int cnt = deg[node];
  float acc = 0.f;
  if (lane < 40) {
    for (int j = 0; j < cnt; ++j) {
      int c = col[start + j];
      acc += H[(size_t)c * 40 + lane];
    }
    acc = fmaf(acc, dinv[node], bias[lane]);
  }
  float v = (lane < 40) ? acc : -INFINITY;
  float m = v;
#pragma unroll
  for (int off = 32; off > 0; off >>= 1) m = fmaxf(m, __shfl_xor(m, off, 64));
  float e = (lane < 40) ? __expf(acc - m) : 0.f;
  float s = e;
#pragma unroll
  for (int off = 32; off > 0; off >>= 1) s += __shfl_xor(s, off, 64);
  if (lane < 40) out[(size_t)node * 40 + lane] = acc - m - __logf(s);
}

// ---------------- launcher ----------------

extern "C" void kernel_launch(void* const* d_in, const int* in_sizes, int n_in,
                              void* d_out, int out_size, void* d_ws, size_t ws_size,
                              hipStream_t stream) {
  const float* x  = (const float*)d_in[0];
  const int* edge = (const int*)d_in[1];
  const float* W1 = (const float*)d_in[2];
  const float* b1 = (const float*)d_in[3];
  const float* W2 = (const float*)d_in[4];
  const float* b2 = (const float*)d_in[5];
  const float* W3 = (const float*)d_in[6];
  const float* b3 = (const float*)d_in[7];
  const float* W4 = (const float*)d_in[8];
  const float* b4 = (const float*)d_in[9];
  float* out = (float*)d_out;

  const int n = N_NODES, E = N_EDGES;
  const int* srcp = edge;        // edge_index[0]
  const int* dstp = edge + E;    // edge_index[1]

  char* ws = (char*)d_ws;
  size_t off = 0;
  auto alloc = [&](size_t bytes) -> void* {
    void* p = ws + off;
    off = (off + bytes + 255) & ~(size_t)255;
    return p;
  };
  int*   deg     = (int*)alloc((size_t)n * 4);
  int*   row_ptr = (int*)alloc((size_t)n * 4);
  int*   fillpos = (int*)alloc((size_t)n * 4);
  float* dinv    = (float*)alloc((size_t)n * 4);
  int*   counter = (int*)alloc(256);
  int*   colx    = (int*)alloc((size_t)(E + n) * 4);
  float* Hbuf    = (float*)alloc((size_t)n * 128 * 4);
  float* Xbuf    = (float*)alloc((size_t)n * 128 * 4);
  (void)ws_size; (void)in_sizes; (void)n_in; (void)out_size;

  k_init <<<(n + 255) / 256, 256, 0, stream>>>(deg, counter, n);
  k_count<<<(E + 255) / 256, 256, 0, stream>>>(dstp, deg, E);
  k_alloc<<<(n + 255) / 256, 256, 0, stream>>>(deg, row_ptr, fillpos, colx, dinv, counter, n);
  k_fill <<<(E + 255) / 256, 256, 0, stream>>>(srcp, dstp, fillpos, colx, E);

  // layer 1
  k_gemm128<<<(n + 63) / 64, 256, 0, stream>>>(x, W1, dinv, Hbuf, n);
  k_agg128 <<<(n + 3) / 4, 256, 0, stream>>>(Hbuf, colx, row_ptr, deg, dinv, b1, Xbuf, n);
  // layer 2
  k_gemm128<<<(n + 63) / 64, 256, 0, stream>>>(Xbuf, W2, dinv, Hbuf, n);
  k_agg128 <<<(n + 3) / 4, 256, 0, stream>>>(Hbuf, colx, row_ptr, deg, dinv, b2, Xbuf, n);
  // layer 3
  k_gemm128<<<(n + 63) / 64, 256, 0, stream>>>(Xbuf, W3, dinv, Hbuf, n);
  k_agg128 <<<(n + 3) / 4, 256, 0, stream>>>(Hbuf, colx, row_ptr, deg, dinv, b3, Xbuf, n);
  // layer 4 (reuse Hbuf as [n][40]) + fused bias/log_softmax
  k_gemm40 <<<(n + 31) / 32, 256, 0, stream>>>(Xbuf, W4, dinv, Hbuf, n);
  k_agg40_lsm<<<(n + 3) / 4, 256, 0, stream>>>(Hbuf, colx, row_ptr, deg, dinv, b4, out, n);
}

// Round 2
// 685.191 us; speedup vs baseline: 1.1073x; 1.1073x over previous
//
#include <hip/hip_runtime.h>
#include <math.h>

#define N_NODES 100000
#define N_EDGES 640000

// ---------------- edge prep ----------------

__global__ __launch_bounds__(256) void k_init(int* __restrict__ deg, int* __restrict__ counter, int n) {
  int i = blockIdx.x * 256 + threadIdx.x;
  if (i < n) deg[i] = 1;            // self-loop
  if (i == 0) *counter = 0;
}

__global__ __launch_bounds__(256) void k_count(const int* __restrict__ dst, int* __restrict__ deg, int e) {
  int i = blockIdx.x * 256 + threadIdx.x;
  if (i < e) atomicAdd(&deg[dst[i]], 1);
}

// per-block exclusive scan + atomic base allocation -> CSR row offsets (order across blocks irrelevant)
__global__ __launch_bounds__(256) void k_alloc(const int* __restrict__ deg, int* __restrict__ row_ptr,
                                               int* __restrict__ fillpos, int* __restrict__ col,
                                               float* __restrict__ dinv, int* __restrict__ counter, int n) {
  __shared__ int sdata[256];
  __shared__ int sbase;
  int tid = threadIdx.x;
  int i = blockIdx.x * 256 + tid;
  int d = (i < n) ? deg[i] : 0;
  sdata[tid] = d;
  __syncthreads();
  for (int off = 1; off < 256; off <<= 1) {
    int v = (tid >= off) ? sdata[tid - off] : 0;
    __syncthreads();
    sdata[tid] += v;
    __syncthreads();
  }
  if (tid == 255) sbase = atomicAdd(counter, sdata[255]);
  __syncthreads();
  int base = sbase;
  if (i < n) {
    int rp = base + sdata[tid] - d;   // exclusive prefix
    row_ptr[i] = rp;
    fillpos[i] = rp + 1;              // slot 0 = self-loop
    col[rp] = i;
    dinv[i] = rsqrtf((float)d);
  }
}

__global__ __launch_bounds__(256) void k_fill(const int* __restrict__ src, const int* __restrict__ dst,
                                              int* __restrict__ fillpos, int* __restrict__ col, int e) {
  int i = blockIdx.x * 256 + threadIdx.x;
  if (i < e) {
    int d = dst[i];
    int p = atomicAdd(&fillpos[d], 1);
    col[p] = src[i];
  }
}

// ---------------- dense GEMM: H[r][c] = dinv[r] * sum_k X[r][k] * W[k][c], N=128 ----------------
// 64 rows/block, 256 threads, 4x8 microtile, K staged in chunks of 32.

__global__ __launch_bounds__(256) void k_gemm128(const float* __restrict__ X, const float* __restrict__ W,
                                                 const float* __restrict__ dinv, float* __restrict__ H, int n) {
  __shared__ float sW[32 * 128];   // [kr][c]
  __shared__ float sX[64 * 36];    // [row][kk], pad 36 (16B-aligned rows, 2-way bank alias only)
  int tid = threadIdx.x;
  int row0 = blockIdx.x * 64;
  int g = tid & 15;          // col group
  int rq = tid >> 4;         // row quad
  int c0 = g * 8;

  float acc[4][8];
#pragma unroll
  for (int i = 0; i < 4; ++i)
#pragma unroll
    for (int j = 0; j < 8; ++j) acc[i][j] = 0.f;

  for (int kc = 0; kc < 4; ++kc) {
    int k0 = kc * 32;
    __syncthreads();
    // stage W chunk (32x128 = 1024 float4)
    {
      const float4* W4 = (const float4*)W;
      float4* sW4 = (float4*)sW;
#pragma unroll
      for (int i = 0; i < 4; ++i) {
        int f = tid + i * 256;           // [0,1024): kr = f/32, c4 = f%32
        sW4[f] = W4[(size_t)(k0 + (f >> 5)) * 32 + (f & 31)];
      }
    }
    // stage X chunk (64 rows x 32 k = 512 float4)
    {
      const float4* X4 = (const float4*)X;
#pragma unroll
      for (int i = 0; i < 2; ++i) {
        int f = tid + i * 256;           // [0,512): row = f/8, k4 = f%8
        int row = f >> 3;
        int k4 = f & 7;
        int grow = row0 + row;
        if (grow >= n) grow = n - 1;     // clamp (result unused)
        float4 v = X4[(size_t)grow * 32 + (k0 >> 2) + k4];
        *((float4*)&sX[row * 36 + k4 * 4]) = v;
      }
    }
    __syncthreads();
#pragma unroll
    for (int k = 0; k < 32; ++k) {
      float a[4];
#pragma unroll
      for (int i = 0; i < 4; ++i) a[i] = sX[(rq * 4 + i) * 36 + k];
      float4 w0 = *((const float4*)&sW[k * 128 + c0]);
      float4 w1 = *((const float4*)&sW[k * 128 + c0 + 4]);
      float w[8] = {w0.x, w0.y, w0.z, w0.w, w1.x, w1.y, w1.z, w1.w};
#pragma unroll
      for (int i = 0; i < 4; ++i)
#pragma unroll
        for (int j = 0; j < 8; ++j) acc[i][j] = fmaf(a[i], w[j], acc[i][j]);
    }
  }
#pragma unroll
  for (int i = 0; i < 4; ++i) {
    int row = row0 + rq * 4 + i;
    if (row < n) {
      float di = dinv[row];
      float4 o0 = make_float4(acc[i][0] * di, acc[i][1] * di, acc[i][2] * di, acc[i][3] * di);
      float4 o1 = make_float4(acc[i][4] * di, acc[i][5] * di, acc[i][6] * di, acc[i][7] * di);
      float4* H4 = (float4*)H;
      H4[(size_t)row * 32 + g * 2] = o0;
      H4[(size_t)row * 32 + g * 2 + 1] = o1;
    }
  }
}

// ---------------- dense GEMM, N=40 (layer 4): tiled like k_gemm128, cols zero-padded to 64 ----------------
// 64 rows/block, 256 threads, 4x4 microtile (rows x cols), only cols<40 stored.

__global__ __launch_bounds__(256) void k_gemm40t(const float* __restrict__ X, const float* __restrict__ W,
                                                 const float* __restrict__ dinv, float* __restrict__ H, int n) {
  __shared__ float sW[32 * 64];    // [kr][c], cols 40..63 zero
  __shared__ float sX[64 * 36];    // [row][kk], padded stride
  int tid = threadIdx.x;
  int row0 = blockIdx.x * 64;
  int g = tid & 15;          // col group: cols g*4 .. g*4+3
  int rq = tid >> 4;         // row quad: rows rq*4 .. rq*4+3

  float acc[4][4];
#pragma unroll
  for (int i = 0; i < 4; ++i)
#pragma unroll
    for (int j = 0; j < 4; ++j) acc[i][j] = 0.f;

  for (int kc = 0; kc < 4; ++kc) {
    int k0 = kc * 32;
    __syncthreads();
    // stage W chunk (32 k-rows x 64 cols = 512 float4), zero-pad cols >= 40
    {
      const float4* W4 = (const float4*)W;   // W is [128][40], 10 float4 per row
      float4* sW4 = (float4*)sW;
#pragma unroll
      for (int i = 0; i < 2; ++i) {
        int f = tid + i * 256;               // [0,512): kr = f/16, c4 = f%16
        int kr = f >> 4;
        int c4 = f & 15;
        float4 v = make_float4(0.f, 0.f, 0.f, 0.f);
        if (c4 < 10) v = W4[(size_t)(k0 + kr) * 10 + c4];
        sW4[f] = v;
      }
    }
    // stage X chunk (64 rows x 32 k = 512 float4)
    {
      const float4* X4 = (const float4*)X;
#pragma unroll
      for (int i = 0; i < 2; ++i) {
        int f = tid + i * 256;               // [0,512): row = f/8, k4 = f%8
        int row = f >> 3;
        int k4 = f & 7;
        int grow = row0 + row;
        if (grow >= n) grow = n - 1;         // clamp (result unused)
        float4 v = X4[(size_t)grow * 32 + (k0 >> 2) + k4];
        *((float4*)&sX[row * 36 + k4 * 4]) = v;
      }
    }
    __syncthreads();
#pragma unroll
    for (int k = 0; k < 32; ++k) {
      float a[4];
#pragma unroll
      for (int i = 0; i < 4; ++i) a[i] = sX[(rq * 4 + i) * 36 + k];
      float4 w = *((const float4*)&sW[k * 64 + g * 4]);
      float wv[4] = {w.x, w.y, w.z, w.w};
#pragma unroll
      for (int i = 0; i < 4; ++i)
#pragma unroll
        for (int j = 0; j < 4; ++j) acc[i][j] = fmaf(a[i], wv[j], acc[i][j]);
    }
  }
  if (g < 10) {
#pragma unroll
    for (int i = 0; i < 4; ++i) {
      int row = row0 + rq * 4 + i;
      if (row < n) {
        float di = dinv[row];
        ((float4*)H)[(size_t)row * 10 + g] =
            make_float4(acc[i][0] * di, acc[i][1] * di, acc[i][2] * di, acc[i][3] * di);
      }
    }
  }
}

// ---------------- aggregation F=128: X_out[i] = relu(dinv[i]*sum_{s in N(i)} H[s] + b) ----------------

__global__ __launch_bounds__(256) void k_agg128(const float* __restrict__ H, const int* __restrict__ col,
                                                const int* __restrict__ row_ptr, const int* __restrict__ deg,
                                                const float* __restrict__ dinv, const float* __restrict__ bias,
                                                float* __restrict__ Xout, int n) {
  int node = blockIdx.x * 4 + (threadIdx.x >> 6);
  int lane = threadIdx.x & 63;
  if (node >= n) return;
  const float2* H2 = (const float2*)H;
  int start = row_ptr[node];
  int cnt = deg[node];
  float ax = 0.f, ay = 0.f;
  for (int j = 0; j < cnt; ++j) {
    int c = col[start + j];
    float2 v = H2[(size_t)c * 64 + lane];
    ax += v.x; ay += v.y;
  }
  float di = dinv[node];
  float2 b = ((const float2*)bias)[lane];
  float o0 = fmaf(ax, di, b.x);
  float o1 = fmaf(ay, di, b.y);
  o0 = o0 > 0.f ? o0 : 0.f;
  o1 = o1 > 0.f ? o1 : 0.f;
  ((float2*)Xout)[(size_t)node * 64 + lane] = make_float2(o0, o1);
}

// ---------------- aggregation F=40 + bias + log_softmax fused ----------------

__global__ __launch_bounds__(256) void k_agg40_lsm(const float* __restrict__ H, const int* __restrict__ col,
                                                   const int* __restrict__ row_ptr, const int* __restrict__ deg,
                                                   const float* __restrict__ dinv, const float* __restrict__ bias,
                                                   float* __restrict__ out, int n) {
  int node = blockIdx.x * 4 + (threadIdx.x >> 6);
  int lane = threadIdx.x & 63;
  if (node >= n) return;
  int start = row_ptr[node];
  int cnt = deg[node];
  float acc = 0.f;
  if (lane < 40) {
    for (int j = 0; j < cnt; ++j) {
      int c = col[start + j];
      acc += H[(size_t)c * 40 + lane];
    }
    acc = fmaf(acc, dinv[node], bias[lane]);
  }
  float v = (lane < 40) ? acc : -INFINITY;
  float m = v;
#pragma unroll
  for (int off = 32; off > 0; off >>= 1) m = fmaxf(m, __shfl_xor(m, off, 64));
  float e = (lane < 40) ? __expf(acc - m) : 0.f;
  float s = e;
#pragma unroll
  for (int off = 32; off > 0; off >>= 1) s += __shfl_xor(s, off, 64);
  if (lane < 40) out[(size_t)node * 40 + lane] = acc - m - __logf(s);
}

// ---------------- launcher ----------------

extern "C" void kernel_launch(void* const* d_in, const int* in_sizes, int n_in,
                              void* d_out, int out_size, void* d_ws, size_t ws_size,
                              hipStream_t stream) {
  const float* x  = (const float*)d_in[0];
  const int* edge = (const int*)d_in[1];
  const float* W1 = (const float*)d_in[2];
  const float* b1 = (const float*)d_in[3];
  const float* W2 = (const float*)d_in[4];
  const float* b2 = (const float*)d_in[5];
  const float* W3 = (const float*)d_in[6];
  const float* b3 = (const float*)d_in[7];
  const float* W4 = (const float*)d_in[8];
  const float* b4 = (const float*)d_in[9];
  float* out = (float*)d_out;

  const int n = N_NODES, E = N_EDGES;
  const int* srcp = edge;        // edge_index[0]
  const int* dstp = edge + E;    // edge_index[1]

  char* ws = (char*)d_ws;
  size_t off = 0;
  auto alloc = [&](size_t bytes) -> void* {
    void* p = ws + off;
    off = (off + bytes + 255) & ~(size_t)255;
    return p;
  };
  int*   deg     = (int*)alloc((size_t)n * 4);
  int*   row_ptr = (int*)alloc((size_t)n * 4);
  int*   fillpos = (int*)alloc((size_t)n * 4);
  float* dinv    = (float*)alloc((size_t)n * 4);
  int*   counter = (int*)alloc(256);
  int*   colx    = (int*)alloc((size_t)(E + n) * 4);
  float* Hbuf    = (float*)alloc((size_t)n * 128 * 4);
  float* Xbuf    = (float*)alloc((size_t)n * 128 * 4);
  (void)ws_size; (void)in_sizes; (void)n_in; (void)out_size;

  k_init <<<(n + 255) / 256, 256, 0, stream>>>(deg, counter, n);
  k_count<<<(E + 255) / 256, 256, 0, stream>>>(dstp, deg, E);
  k_alloc<<<(n + 255) / 256, 256, 0, stream>>>(deg, row_ptr, fillpos, colx, dinv, counter, n);
  k_fill <<<(E + 255) / 256, 256, 0, stream>>>(srcp, dstp, fillpos, colx, E);

  // layer 1
  k_gemm128<<<(n + 63) / 64, 256, 0, stream>>>(x, W1, dinv, Hbuf, n);
  k_agg128 <<<(n + 3) / 4, 256, 0, stream>>>(Hbuf, colx, row_ptr, deg, dinv, b1, Xbuf, n);
  // layer 2
  k_gemm128<<<(n + 63) / 64, 256, 0, stream>>>(Xbuf, W2, dinv, Hbuf, n);
  k_agg128 <<<(n + 3) / 4, 256, 0, stream>>>(Hbuf, colx, row_ptr, deg, dinv, b2, Xbuf, n);
  // layer 3
  k_gemm128<<<(n + 63) / 64, 256, 0, stream>>>(Xbuf, W3, dinv, Hbuf, n);
  k_agg128 <<<(n + 3) / 4, 256, 0, stream>>>(Hbuf, colx, row_ptr, deg, dinv, b3, Xbuf, n);
  // layer 4 (reuse Hbuf as [n][40]) + fused bias/log_softmax
  k_gemm40t<<<(n + 63) / 64, 256, 0, stream>>>(Xbuf, W4, dinv, Hbuf, n);
  k_agg40_lsm<<<(n + 3) / 4, 256, 0, stream>>>(Hbuf, colx, row_ptr, deg, dinv, b4, out, n);
}

// Round 3
// 412.877 us; speedup vs baseline: 1.8376x; 1.6596x over previous
//
#include <hip/hip_runtime.h>
#include <math.h>

#define N_NODES 100000
#define N_EDGES 640000

typedef __bf16 bf16x8 __attribute__((ext_vector_type(8)));
typedef float f32x4 __attribute__((ext_vector_type(4)));

__device__ __forceinline__ unsigned short f2b(float x) {
  unsigned int u = __float_as_uint(x);
  u = (u + 0x7FFFu + ((u >> 16) & 1u)) >> 16;   // RNE
  return (unsigned short)u;
}
__device__ __forceinline__ float blo(unsigned int v) { return __uint_as_float(v << 16); }
__device__ __forceinline__ float bhi(unsigned int v) { return __uint_as_float(v & 0xFFFF0000u); }

// ---------------- edge prep ----------------

__global__ __launch_bounds__(256) void k_init(int* __restrict__ deg, int* __restrict__ counter, int n) {
  int i = blockIdx.x * 256 + threadIdx.x;
  if (i < n) deg[i] = 1;            // self-loop
  if (i == 0) *counter = 0;
}

__global__ __launch_bounds__(256) void k_count(const int* __restrict__ dst, int* __restrict__ deg, int e) {
  int i = blockIdx.x * 256 + threadIdx.x;
  if (i < e) atomicAdd(&deg[dst[i]], 1);
}

__global__ __launch_bounds__(256) void k_alloc(const int* __restrict__ deg, int* __restrict__ row_ptr,
                                               int* __restrict__ fillpos, int* __restrict__ col,
                                               float* __restrict__ dinv, int* __restrict__ counter, int n) {
  __shared__ int sdata[256];
  __shared__ int sbase;
  int tid = threadIdx.x;
  int i = blockIdx.x * 256 + tid;
  int d = (i < n) ? deg[i] : 0;
  sdata[tid] = d;
  __syncthreads();
  for (int off = 1; off < 256; off <<= 1) {
    int v = (tid >= off) ? sdata[tid - off] : 0;
    __syncthreads();
    sdata[tid] += v;
    __syncthreads();
  }
  if (tid == 255) sbase = atomicAdd(counter, sdata[255]);
  __syncthreads();
  int base = sbase;
  if (i < n) {
    int rp = base + sdata[tid] - d;   // exclusive prefix
    row_ptr[i] = rp;
    fillpos[i] = rp + 1;              // slot 0 = self-loop
    col[rp] = i;
    dinv[i] = rsqrtf((float)d);
  }
}

__global__ __launch_bounds__(256) void k_fill(const int* __restrict__ src, const int* __restrict__ dst,
                                              int* __restrict__ fillpos, int* __restrict__ col, int e) {
  int i = blockIdx.x * 256 + threadIdx.x;
  if (i < e) {
    int d = dst[i];
    int p = atomicAdd(&fillpos[d], 1);
    col[p] = src[i];
  }
}

// ---------------- fp32 -> bf16 cast of X ----------------

__global__ __launch_bounds__(256) void k_cast(const float4* __restrict__ X4, uint4* __restrict__ Xb4, int n8) {
  int i = blockIdx.x * 256 + threadIdx.x;
  if (i >= n8) return;
  float4 a = X4[(size_t)i * 2];
  float4 b = X4[(size_t)i * 2 + 1];
  uint4 o;
  o.x = (unsigned int)f2b(a.x) | ((unsigned int)f2b(a.y) << 16);
  o.y = (unsigned int)f2b(a.z) | ((unsigned int)f2b(a.w) << 16);
  o.z = (unsigned int)f2b(b.x) | ((unsigned int)f2b(b.y) << 16);
  o.w = (unsigned int)f2b(b.z) | ((unsigned int)f2b(b.w) << 16);
  Xb4[i] = o;
}

// transpose 128x128 fp32 W -> bf16 Wt[n][k]
__global__ __launch_bounds__(256) void k_prepW(const float* __restrict__ W, unsigned short* __restrict__ Wt) {
  int idx = blockIdx.x * 256 + threadIdx.x;   // 16384
  int k = idx >> 7, nn = idx & 127;
  Wt[nn * 128 + k] = f2b(W[idx]);
}

// ---------------- MFMA bf16 GEMM: H[r][c] = bf16(dinv[r] * sum_k X[r][k]*W[k][c]), 128 cols ----------------
// 64 rows/block, 256 threads (4 waves x 16 rows), whole K=128 staged once.

#define SXP 136   // padded LDS stride in bf16 elems (272 B: 16B-aligned, 2-way bank alias only)

__global__ __launch_bounds__(256) void k_gemmb(const unsigned short* __restrict__ Xb,
                                               const unsigned short* __restrict__ Wt,
                                               const float* __restrict__ dinv,
                                               unsigned short* __restrict__ H, int n) {
  __shared__ unsigned short sX[64 * SXP];
  __shared__ unsigned short sW[128 * SXP];   // [n][k]
  int tid = threadIdx.x;
  int row0 = blockIdx.x * 64;
  // stage W^T (128 x 128 bf16 = 2048 x 16B)
  {
    const uint4* Wt4 = (const uint4*)Wt;
#pragma unroll
    for (int i = 0; i < 8; ++i) {
      int f = tid + i * 256;
      int nn = f >> 4, k8 = f & 15;
      *(uint4*)&sW[nn * SXP + k8 * 8] = Wt4[f];
    }
  }
  // stage X rows (64 x 128 bf16 = 1024 x 16B)
  {
    const uint4* Xb4 = (const uint4*)Xb;
#pragma unroll
    for (int i = 0; i < 4; ++i) {
      int f = tid + i * 256;
      int r = f >> 4, k8 = f & 15;
      int grow = row0 + r;
      if (grow >= n) grow = n - 1;
      *(uint4*)&sX[r * SXP + k8 * 8] = Xb4[(size_t)grow * 16 + k8];
    }
  }
  __syncthreads();
  int wave = tid >> 6, lane = tid & 63;
  int m = lane & 15, q = lane >> 4;
  f32x4 acc[8];
#pragma unroll
  for (int ct = 0; ct < 8; ++ct) acc[ct] = (f32x4){0.f, 0.f, 0.f, 0.f};
#pragma unroll
  for (int kc = 0; kc < 4; ++kc) {
    bf16x8 a = *(const bf16x8*)&sX[(wave * 16 + m) * SXP + kc * 32 + q * 8];
#pragma unroll
    for (int ct = 0; ct < 8; ++ct) {
      bf16x8 b = *(const bf16x8*)&sW[(ct * 16 + m) * SXP + kc * 32 + q * 8];
      acc[ct] = __builtin_amdgcn_mfma_f32_16x16x32_bf16(a, b, acc[ct], 0, 0, 0);
    }
  }
  // epilogue: D row = wave*16 + q*4 + r, col = ct*16 + m
#pragma unroll
  for (int r = 0; r < 4; ++r) {
    int row = row0 + wave * 16 + q * 4 + r;
    if (row < n) {
      float di = dinv[row];
#pragma unroll
      for (int ct = 0; ct < 8; ++ct) {
        H[(size_t)row * 128 + ct * 16 + m] = f2b(acc[ct][r] * di);
      }
    }
  }
}

// ---------------- aggregation F=128 bf16: Xout[i] = bf16(relu(dinv[i]*sum H[s] + b)) ----------------
// one wave per node; lane-parallel col prefetch + 4-wide gather ILP.

__global__ __launch_bounds__(256) void k_aggb(const unsigned short* __restrict__ H, const int* __restrict__ col,
                                              const int* __restrict__ row_ptr, const int* __restrict__ deg,
                                              const float* __restrict__ dinv, const float* __restrict__ bias,
                                              unsigned short* __restrict__ Xout, int n) {
  int node = blockIdx.x * 4 + (threadIdx.x >> 6);
  int lane = threadIdx.x & 63;
  if (node >= n) return;
  const unsigned int* H1 = (const unsigned int*)H;   // 2 bf16 per uint, 64 per row
  int start = row_ptr[node];
  int cnt = deg[node];
  float ax = 0.f, ay = 0.f;
  int myc = (lane < cnt) ? col[start + lane] : 0;
  int lim = (cnt < 64) ? cnt : 64;
  int j = 0;
  for (; j + 4 <= lim; j += 4) {
    int c0 = __shfl(myc, j, 64);
    int c1 = __shfl(myc, j + 1, 64);
    int c2 = __shfl(myc, j + 2, 64);
    int c3 = __shfl(myc, j + 3, 64);
    unsigned int v0 = H1[(size_t)c0 * 64 + lane];
    unsigned int v1 = H1[(size_t)c1 * 64 + lane];
    unsigned int v2 = H1[(size_t)c2 * 64 + lane];
    unsigned int v3 = H1[(size_t)c3 * 64 + lane];
    ax += (blo(v0) + blo(v1)) + (blo(v2) + blo(v3));
    ay += (bhi(v0) + bhi(v1)) + (bhi(v2) + bhi(v3));
  }
  for (; j < lim; ++j) {
    int c = __shfl(myc, j, 64);
    unsigned int v = H1[(size_t)c * 64 + lane];
    ax += blo(v); ay += bhi(v);
  }
  for (; j < cnt; ++j) {                 // cnt > 64 overflow (rare)
    int c = col[start + j];
    unsigned int v = H1[(size_t)c * 64 + lane];
    ax += blo(v); ay += bhi(v);
  }
  float di = dinv[node];
  float2 b = ((const float2*)bias)[lane];
  float o0 = fmaf(ax, di, b.x);
  float o1 = fmaf(ay, di, b.y);
  o0 = o0 > 0.f ? o0 : 0.f;
  o1 = o1 > 0.f ? o1 : 0.f;
  ((unsigned int*)Xout)[(size_t)node * 64 + lane] =
      (unsigned int)f2b(o0) | ((unsigned int)f2b(o1) << 16);
}

// ---------------- dense GEMM, N=40 (layer 4), bf16 input, fp32 compute ----------------

__global__ __launch_bounds__(256) void k_gemm40t(const unsigned short* __restrict__ Xb, const float* __restrict__ W,
                                                 const float* __restrict__ dinv, float* __restrict__ H, int n) {
  __shared__ float sW[32 * 64];    // [kr][c], cols 40..63 zero
  __shared__ float sX[64 * 36];    // [row][kk], padded stride
  int tid = threadIdx.x;
  int row0 = blockIdx.x * 64;
  int g = tid & 15;
  int rq = tid >> 4;

  float acc[4][4];
#pragma unroll
  for (int i = 0; i < 4; ++i)
#pragma unroll
    for (int j = 0; j < 4; ++j) acc[i][j] = 0.f;

  for (int kc = 0; kc < 4; ++kc) {
    int k0 = kc * 32;
    __syncthreads();
    {
      const float4* W4 = (const float4*)W;   // W is [128][40]
      float4* sW4 = (float4*)sW;
#pragma unroll
      for (int i = 0; i < 2; ++i) {
        int f = tid + i * 256;
        int kr = f >> 4;
        int c4 = f & 15;
        float4 v = make_float4(0.f, 0.f, 0.f, 0.f);
        if (c4 < 10) v = W4[(size_t)(k0 + kr) * 10 + c4];
        sW4[f] = v;
      }
    }
    {
      const uint2* Xb2 = (const uint2*)Xb;   // 4 bf16, row = 32 units
#pragma unroll
      for (int i = 0; i < 2; ++i) {
        int f = tid + i * 256;
        int row = f >> 3;
        int k4 = f & 7;
        int grow = row0 + row;
        if (grow >= n) grow = n - 1;
        uint2 v = Xb2[(size_t)grow * 32 + (k0 >> 2) + k4];
        float4 fv;
        fv.x = blo(v.x); fv.y = bhi(v.x); fv.z = blo(v.y); fv.w = bhi(v.y);
        *((float4*)&sX[row * 36 + k4 * 4]) = fv;
      }
    }
    __syncthreads();
#pragma unroll
    for (int k = 0; k < 32; ++k) {
      float a[4];
#pragma unroll
      for (int i = 0; i < 4; ++i) a[i] = sX[(rq * 4 + i) * 36 + k];
      float4 w = *((const float4*)&sW[k * 64 + g * 4]);
      float wv[4] = {w.x, w.y, w.z, w.w};
#pragma unroll
      for (int i = 0; i < 4; ++i)
#pragma unroll
        for (int j = 0; j < 4; ++j) acc[i][j] = fmaf(a[i], wv[j], acc[i][j]);
    }
  }
  if (g < 10) {
#pragma unroll
    for (int i = 0; i < 4; ++i) {
      int row = row0 + rq * 4 + i;
      if (row < n) {
        float di = dinv[row];
        ((float4*)H)[(size_t)row * 10 + g] =
            make_float4(acc[i][0] * di, acc[i][1] * di, acc[i][2] * di, acc[i][3] * di);
      }
    }
  }
}

// ---------------- aggregation F=40 + bias + log_softmax fused (fp32 H, ILP gather) ----------------

__global__ __launch_bounds__(256) void k_agg40_lsm(const float* __restrict__ H, const int* __restrict__ col,
                                                   const int* __restrict__ row_ptr, const int* __restrict__ deg,
                                                   const float* __restrict__ dinv, const float* __restrict__ bias,
                                                   float* __restrict__ out, int n) {
  int node = blockIdx.x * 4 + (threadIdx.x >> 6);
  int lane = threadIdx.x & 63;
  if (node >= n) return;
  int start = row_ptr[node];
  int cnt = deg[node];
  int cl = (lane < 40) ? lane : 39;
  float acc = 0.f;
  int myc = (lane < cnt) ? col[start + lane] : 0;
  int lim = (cnt < 64) ? cnt : 64;
  int j = 0;
  for (; j + 4 <= lim; j += 4) {
    int c0 = __shfl(myc, j, 64);
    int c1 = __shfl(myc, j + 1, 64);
    int c2 = __shfl(myc, j + 2, 64);
    int c3 = __shfl(myc, j + 3, 64);
    float v0 = H[(size_t)c0 * 40 + cl];
    float v1 = H[(size_t)c1 * 40 + cl];
    float v2 = H[(size_t)c2 * 40 + cl];
    float v3 = H[(size_t)c3 * 40 + cl];
    acc += (v0 + v1) + (v2 + v3);
  }
  for (; j < lim; ++j) {
    int c = __shfl(myc, j, 64);
    acc += H[(size_t)c * 40 + cl];
  }
  for (; j < cnt; ++j) {
    int c = col[start + j];
    acc += H[(size_t)c * 40 + cl];
  }
  acc = fmaf(acc, dinv[node], bias[cl]);
  float v = (lane < 40) ? acc : -INFINITY;
  float m = v;
#pragma unroll
  for (int off = 32; off > 0; off >>= 1) m = fmaxf(m, __shfl_xor(m, off, 64));
  float e = (lane < 40) ? __expf(acc - m) : 0.f;
  float s = e;
#pragma unroll
  for (int off = 32; off > 0; off >>= 1) s += __shfl_xor(s, off, 64);
  if (lane < 40) out[(size_t)node * 40 + lane] = acc - m - __logf(s);
}

// ---------------- launcher ----------------

extern "C" void kernel_launch(void* const* d_in, const int* in_sizes, int n_in,
                              void* d_out, int out_size, void* d_ws, size_t ws_size,
                              hipStream_t stream) {
  const float* x  = (const float*)d_in[0];
  const int* edge = (const int*)d_in[1];
  const float* W1 = (const float*)d_in[2];
  const float* b1 = (const float*)d_in[3];
  const float* W2 = (const float*)d_in[4];
  const float* b2 = (const float*)d_in[5];
  const float* W3 = (const float*)d_in[6];
  const float* b3 = (const float*)d_in[7];
  const float* W4 = (const float*)d_in[8];
  const float* b4 = (const float*)d_in[9];
  float* out = (float*)d_out;

  const int n = N_NODES, E = N_EDGES;
  const int* srcp = edge;        // edge_index[0]
  const int* dstp = edge + E;    // edge_index[1]

  char* ws = (char*)d_ws;
  size_t off = 0;
  auto alloc = [&](size_t bytes) -> void* {
    void* p = ws + off;
    off = (off + bytes + 255) & ~(size_t)255;
    return p;
  };
  int*   deg     = (int*)alloc((size_t)n * 4);
  int*   row_ptr = (int*)alloc((size_t)n * 4);
  int*   fillpos = (int*)alloc((size_t)n * 4);
  float* dinv    = (float*)alloc((size_t)n * 4);
  int*   counter = (int*)alloc(256);
  int*   colx    = (int*)alloc((size_t)(E + n) * 4);
  unsigned short* Xb = (unsigned short*)alloc((size_t)n * 128 * 2);
  unsigned short* Hb = (unsigned short*)alloc((size_t)n * 128 * 2);  // also reused as fp32 H4 [n][40]
  unsigned short* Xc = (unsigned short*)alloc((size_t)n * 128 * 2);
  unsigned short* Wt = (unsigned short*)alloc((size_t)3 * 128 * 128 * 2);
  float* H4 = (float*)Hb;   // n*40*4 = 16 MB <= 25.6 MB, gemm40 doesn't read Hb
  (void)ws_size; (void)in_sizes; (void)n_in; (void)out_size;

  k_init <<<(n + 255) / 256, 256, 0, stream>>>(deg, counter, n);
  k_count<<<(E + 255) / 256, 256, 0, stream>>>(dstp, deg, E);
  k_alloc<<<(n + 255) / 256, 256, 0, stream>>>(deg, row_ptr, fillpos, colx, dinv, counter, n);
  k_fill <<<(E + 255) / 256, 256, 0, stream>>>(srcp, dstp, fillpos, colx, E);

  k_cast <<<6250, 256, 0, stream>>>((const float4*)x, (uint4*)Xb, n * 128 / 8);
  k_prepW<<<64, 256, 0, stream>>>(W1, Wt);
  k_prepW<<<64, 256, 0, stream>>>(W2, Wt + 16384);
  k_prepW<<<64, 256, 0, stream>>>(W3, Wt + 32768);

  const int gg = (n + 63) / 64, ga = (n + 3) / 4;
  // layer 1
  k_gemmb<<<gg, 256, 0, stream>>>(Xb, Wt, dinv, Hb, n);
  k_aggb <<<ga, 256, 0, stream>>>(Hb, colx, row_ptr, deg, dinv, b1, Xc, n);
  // layer 2
  k_gemmb<<<gg, 256, 0, stream>>>(Xc, Wt + 16384, dinv, Hb, n);
  k_aggb <<<ga, 256, 0, stream>>>(Hb, colx, row_ptr, deg, dinv, b2, Xc, n);
  // layer 3
  k_gemmb<<<gg, 256, 0, stream>>>(Xc, Wt + 32768, dinv, Hb, n);
  k_aggb <<<ga, 256, 0, stream>>>(Hb, colx, row_ptr, deg, dinv, b3, Xc, n);
  // layer 4
  k_gemm40t<<<gg, 256, 0, stream>>>(Xc, W4, dinv, H4, n);
  k_agg40_lsm<<<ga, 256, 0, stream>>>(H4, colx, row_ptr, deg, dinv, b4, out, n);
}

// Round 4
// 372.398 us; speedup vs baseline: 2.0373x; 1.1087x over previous
//
#include <hip/hip_runtime.h>
#include <math.h>

#define N_NODES 100000
#define N_EDGES 640000

typedef __bf16 bf16x8 __attribute__((ext_vector_type(8)));
typedef float f32x4 __attribute__((ext_vector_type(4)));

__device__ __forceinline__ unsigned short f2b(float x) {
  unsigned int u = __float_as_uint(x);
  u = (u + 0x7FFFu + ((u >> 16) & 1u)) >> 16;   // RNE
  return (unsigned short)u;
}
__device__ __forceinline__ float blo(unsigned int v) { return __uint_as_float(v << 16); }
__device__ __forceinline__ float bhi(unsigned int v) { return __uint_as_float(v & 0xFFFF0000u); }

// ---------------- edge prep ----------------

__global__ __launch_bounds__(256) void k_init(int* __restrict__ deg, int* __restrict__ counter, int n) {
  int i = blockIdx.x * 256 + threadIdx.x;
  if (i < n) deg[i] = 1;            // self-loop
  if (i == 0) *counter = 0;
}

__global__ __launch_bounds__(256) void k_count(const int* __restrict__ dst, int* __restrict__ deg, int e) {
  int i = blockIdx.x * 256 + threadIdx.x;
  if (i < e) atomicAdd(&deg[dst[i]], 1);
}

__global__ __launch_bounds__(256) void k_alloc(const int* __restrict__ deg, int* __restrict__ row_ptr,
                                               int* __restrict__ fillpos, int* __restrict__ col,
                                               float* __restrict__ dinv, int* __restrict__ counter, int n) {
  __shared__ int sdata[256];
  __shared__ int sbase;
  int tid = threadIdx.x;
  int i = blockIdx.x * 256 + tid;
  int d = (i < n) ? deg[i] : 0;
  sdata[tid] = d;
  __syncthreads();
  for (int off = 1; off < 256; off <<= 1) {
    int v = (tid >= off) ? sdata[tid - off] : 0;
    __syncthreads();
    sdata[tid] += v;
    __syncthreads();
  }
  if (tid == 255) sbase = atomicAdd(counter, sdata[255]);
  __syncthreads();
  int base = sbase;
  if (i < n) {
    int rp = base + sdata[tid] - d;   // exclusive prefix
    row_ptr[i] = rp;
    fillpos[i] = rp + 1;              // slot 0 = self-loop
    col[rp] = i;
    dinv[i] = rsqrtf((float)d);
  }
}

__global__ __launch_bounds__(256) void k_fill(const int* __restrict__ src, const int* __restrict__ dst,
                                              int* __restrict__ fillpos, int* __restrict__ col, int e) {
  int i = blockIdx.x * 256 + threadIdx.x;
  if (i < e) {
    int d = dst[i];
    int p = atomicAdd(&fillpos[d], 1);
    col[p] = src[i];
  }
}

// ---------------- fp32 -> bf16 cast of X ----------------

__global__ __launch_bounds__(256) void k_cast(const float4* __restrict__ X4, uint4* __restrict__ Xb4, int n8) {
  int i = blockIdx.x * 256 + threadIdx.x;
  if (i >= n8) return;
  float4 a = X4[(size_t)i * 2];
  float4 b = X4[(size_t)i * 2 + 1];
  uint4 o;
  o.x = (unsigned int)f2b(a.x) | ((unsigned int)f2b(a.y) << 16);
  o.y = (unsigned int)f2b(a.z) | ((unsigned int)f2b(a.w) << 16);
  o.z = (unsigned int)f2b(b.x) | ((unsigned int)f2b(b.y) << 16);
  o.w = (unsigned int)f2b(b.z) | ((unsigned int)f2b(b.w) << 16);
  Xb4[i] = o;
}

// ---------------- weight prep: W1/2/3 -> bf16 W^T [128][128]; W4 -> bf16 W^T zero-padded [48][128] ----------------

__global__ __launch_bounds__(256) void k_prepW(const float* __restrict__ W1, const float* __restrict__ W2,
                                               const float* __restrict__ W3, const float* __restrict__ W4,
                                               unsigned short* __restrict__ Wt, unsigned short* __restrict__ Wt4) {
  int b = blockIdx.x;
  if (b < 192) {
    const float* W = (b < 64) ? W1 : (b < 128) ? W2 : W3;
    unsigned short* D = Wt + ((b < 64) ? 0 : (b < 128) ? 16384 : 32768);
    int idx = (b & 63) * 256 + threadIdx.x;     // [0,16384)
    int k = idx >> 7, nn = idx & 127;
    D[nn * 128 + k] = f2b(W[idx]);
  } else {
    int idx = (b - 192) * 256 + threadIdx.x;    // [0,6144)
    int nn = idx >> 7, k = idx & 127;           // nn in [0,48)
    Wt4[nn * 128 + k] = (nn < 40) ? f2b(W4[(size_t)k * 40 + nn]) : (unsigned short)0;
  }
}

// ---------------- MFMA bf16 GEMM: H[r][c] = bf16(dinv[r]*sum_k X[r][k]*W[k][c]), 128 cols ----------------
// 64 rows/block, 4 waves x 16-row bands; W^T in LDS, A-fragments straight from global.

#define SXP 136   // padded LDS stride in bf16 elems (conflict-free per r2/r3 measurements)

__global__ __launch_bounds__(256) void k_gemmb(const unsigned short* __restrict__ Xb,
                                               const unsigned short* __restrict__ Wt,
                                               const float* __restrict__ dinv,
                                               unsigned short* __restrict__ H, int n) {
  __shared__ unsigned short sW[128 * SXP];   // [n][k]
  int tid = threadIdx.x;
  int row0 = blockIdx.x * 64;
  {
    const uint4* Wt4 = (const uint4*)Wt;
#pragma unroll
    for (int i = 0; i < 8; ++i) {
      int f = tid + i * 256;                 // [0,2048): nn = f/16, k8 = f%16
      *(uint4*)&sW[(f >> 4) * SXP + (f & 15) * 8] = Wt4[f];
    }
  }
  int wave = tid >> 6, lane = tid & 63;
  int m = lane & 15, q = lane >> 4;
  int grow = row0 + wave * 16 + m;
  if (grow >= n) grow = n - 1;
  const uint4* Xb4 = (const uint4*)Xb;
  uint4 a4[4];
#pragma unroll
  for (int kc = 0; kc < 4; ++kc) a4[kc] = Xb4[(size_t)grow * 16 + kc * 4 + q];
  __syncthreads();
  f32x4 acc[8];
#pragma unroll
  for (int ct = 0; ct < 8; ++ct) acc[ct] = (f32x4){0.f, 0.f, 0.f, 0.f};
#pragma unroll
  for (int kc = 0; kc < 4; ++kc) {
    bf16x8 a = *(bf16x8*)&a4[kc];
#pragma unroll
    for (int ct = 0; ct < 8; ++ct) {
      bf16x8 b = *(const bf16x8*)&sW[(ct * 16 + m) * SXP + kc * 32 + q * 8];
      acc[ct] = __builtin_amdgcn_mfma_f32_16x16x32_bf16(a, b, acc[ct], 0, 0, 0);
    }
  }
  // D row = wave*16 + q*4 + r, col = ct*16 + m
#pragma unroll
  for (int r = 0; r < 4; ++r) {
    int row = row0 + wave * 16 + q * 4 + r;
    if (row < n) {
      float di = dinv[row];
#pragma unroll
      for (int ct = 0; ct < 8; ++ct) {
        H[(size_t)row * 128 + ct * 16 + m] = f2b(acc[ct][r] * di);
      }
    }
  }
}

// ---------------- MFMA bf16 GEMM, 48 padded cols (layer 4), bf16 output [n][40] ----------------

__global__ __launch_bounds__(256) void k_gemm48(const unsigned short* __restrict__ Xb,
                                                const unsigned short* __restrict__ Wt4,
                                                const float* __restrict__ dinv,
                                                unsigned short* __restrict__ H, int n) {
  __shared__ unsigned short sW[48 * SXP];
  int tid = threadIdx.x;
  int row0 = blockIdx.x * 64;
  {
    const uint4* W4 = (const uint4*)Wt4;
#pragma unroll
    for (int i = 0; i < 3; ++i) {
      int f = tid + i * 256;                 // [0,768)
      *(uint4*)&sW[(f >> 4) * SXP + (f & 15) * 8] = W4[f];
    }
  }
  int wave = tid >> 6, lane = tid & 63;
  int m = lane & 15, q = lane >> 4;
  int grow = row0 + wave * 16 + m;
  if (grow >= n) grow = n - 1;
  const uint4* Xb4 = (const uint4*)Xb;
  uint4 a4[4];
#pragma unroll
  for (int kc = 0; kc < 4; ++kc) a4[kc] = Xb4[(size_t)grow * 16 + kc * 4 + q];
  __syncthreads();
  f32x4 acc[3];
#pragma unroll
  for (int ct = 0; ct < 3; ++ct) acc[ct] = (f32x4){0.f, 0.f, 0.f, 0.f};
#pragma unroll
  for (int kc = 0; kc < 4; ++kc) {
    bf16x8 a = *(bf16x8*)&a4[kc];
#pragma unroll
    for (int ct = 0; ct < 3; ++ct) {
      bf16x8 b = *(const bf16x8*)&sW[(ct * 16 + m) * SXP + kc * 32 + q * 8];
      acc[ct] = __builtin_amdgcn_mfma_f32_16x16x32_bf16(a, b, acc[ct], 0, 0, 0);
    }
  }
#pragma unroll
  for (int r = 0; r < 4; ++r) {
    int row = row0 + wave * 16 + q * 4 + r;
    if (row < n) {
      float di = dinv[row];
#pragma unroll
      for (int ct = 0; ct < 3; ++ct) {
        int c = ct * 16 + m;
        if (c < 40) H[(size_t)row * 40 + c] = f2b(acc[ct][r] * di);
      }
    }
  }
}

// ---------------- aggregation F=128 bf16, branch-free 8-deep gather MLP ----------------

__global__ __launch_bounds__(256) void k_aggb(const unsigned short* __restrict__ H, const int* __restrict__ col,
                                              const int* __restrict__ row_ptr, const int* __restrict__ deg,
                                              const float* __restrict__ dinv, const float* __restrict__ bias,
                                              unsigned short* __restrict__ Xout, int n) {
  int node = blockIdx.x * 4 + (threadIdx.x >> 6);
  int lane = threadIdx.x & 63;
  if (node >= n) return;
  const unsigned int* H1 = (const unsigned int*)H;   // 2 bf16 per uint, 64 per row
  int start = row_ptr[node];
  int cnt = deg[node];
  int myc = (lane < cnt) ? col[start + lane] : 0;
  int lim = (cnt < 64) ? cnt : 64;
  int last = lim - 1;
  float ax = 0.f, ay = 0.f;
  for (int base = 0; base < lim; base += 8) {
    unsigned int v[8];
#pragma unroll
    for (int jj = 0; jj < 8; ++jj) {
      int idx = base + jj;
      if (idx > last) idx = last;              // clamped dup -> L1 hit, keeps 8 loads in flight
      int c = __shfl(myc, idx, 64);
      v[jj] = H1[(size_t)c * 64 + lane];
    }
#pragma unroll
    for (int jj = 0; jj < 8; ++jj) {
      bool ok = (base + jj) <= last;
      ax += ok ? blo(v[jj]) : 0.f;
      ay += ok ? bhi(v[jj]) : 0.f;
    }
  }
  for (int j = 64; j < cnt; ++j) {             // overflow (deg>64, ~never)
    int c = col[start + j];
    unsigned int v = H1[(size_t)c * 64 + lane];
    ax += blo(v); ay += bhi(v);
  }
  float di = dinv[node];
  float2 b = ((const float2*)bias)[lane];
  float o0 = fmaf(ax, di, b.x);
  float o1 = fmaf(ay, di, b.y);
  o0 = o0 > 0.f ? o0 : 0.f;
  o1 = o1 > 0.f ? o1 : 0.f;
  ((unsigned int*)Xout)[(size_t)node * 64 + lane] =
      (unsigned int)f2b(o0) | ((unsigned int)f2b(o1) << 16);
}

// ---------------- aggregation F=40 (bf16 H) + bias + log_softmax fused ----------------

__global__ __launch_bounds__(256) void k_agg40_lsm(const unsigned short* __restrict__ H, const int* __restrict__ col,
                                                   const int* __restrict__ row_ptr, const int* __restrict__ deg,
                                                   const float* __restrict__ dinv, const float* __restrict__ bias,
                                                   float* __restrict__ out, int n) {
  int node = blockIdx.x * 4 + (threadIdx.x >> 6);
  int lane = threadIdx.x & 63;
  if (node >= n) return;
  int start = row_ptr[node];
  int cnt = deg[node];
  int cl = (lane < 40) ? lane : 39;
  int myc = (lane < cnt) ? col[start + lane] : 0;
  int lim = (cnt < 64) ? cnt : 64;
  int last = lim - 1;
  float acc = 0.f;
  for (int base = 0; base < lim; base += 8) {
    float v[8];
#pragma unroll
    for (int jj = 0; jj < 8; ++jj) {
      int idx = base + jj;
      if (idx > last) idx = last;
      int c = __shfl(myc, idx, 64);
      v[jj] = __uint_as_float(((unsigned int)H[(size_t)c * 40 + cl]) << 16);
    }
#pragma unroll
    for (int jj = 0; jj < 8; ++jj) acc += ((base + jj) <= last) ? v[jj] : 0.f;
  }
  for (int j = 64; j < cnt; ++j)
    acc += __uint_as_float(((unsigned int)H[(size_t)col[start + j] * 40 + cl]) << 16);
  acc = fmaf(acc, dinv[node], bias[cl]);
  float v = (lane < 40) ? acc : -INFINITY;
  float m = v;
#pragma unroll
  for (int off = 32; off > 0; off >>= 1) m = fmaxf(m, __shfl_xor(m, off, 64));
  float e = (lane < 40) ? __expf(acc - m) : 0.f;
  float s = e;
#pragma unroll
  for (int off = 32; off > 0; off >>= 1) s += __shfl_xor(s, off, 64);
  if (lane < 40) out[(size_t)node * 40 + lane] = acc - m - __logf(s);
}

// ---------------- launcher ----------------

extern "C" void kernel_launch(void* const* d_in, const int* in_sizes, int n_in,
                              void* d_out, int out_size, void* d_ws, size_t ws_size,
                              hipStream_t stream) {
  const float* x  = (const float*)d_in[0];
  const int* edge = (const int*)d_in[1];
  const float* W1 = (const float*)d_in[2];
  const float* b1 = (const float*)d_in[3];
  const float* W2 = (const float*)d_in[4];
  const float* b2 = (const float*)d_in[5];
  const float* W3 = (const float*)d_in[6];
  const float* b3 = (const float*)d_in[7];
  const float* W4 = (const float*)d_in[8];
  const float* b4 = (const float*)d_in[9];
  float* out = (float*)d_out;

  const int n = N_NODES, E = N_EDGES;
  const int* srcp = edge;        // edge_index[0]
  const int* dstp = edge + E;    // edge_index[1]

  char* ws = (char*)d_ws;
  size_t off = 0;
  auto alloc = [&](size_t bytes) -> void* {
    void* p = ws + off;
    off = (off + bytes + 255) & ~(size_t)255;
    return p;
  };
  int*   deg     = (int*)alloc((size_t)n * 4);
  int*   row_ptr = (int*)alloc((size_t)n * 4);
  int*   fillpos = (int*)alloc((size_t)n * 4);
  float* dinv    = (float*)alloc((size_t)n * 4);
  int*   counter = (int*)alloc(256);
  int*   colx    = (int*)alloc((size_t)(E + n) * 4);
  unsigned short* Xb  = (unsigned short*)alloc((size_t)n * 128 * 2);
  unsigned short* Hb  = (unsigned short*)alloc((size_t)n * 128 * 2);  // also holds bf16 H4 [n][40]
  unsigned short* Xc  = (unsigned short*)alloc((size_t)n * 128 * 2);
  unsigned short* Wt  = (unsigned short*)alloc((size_t)3 * 128 * 128 * 2);
  unsigned short* Wt4 = (unsigned short*)alloc((size_t)48 * 128 * 2);
  (void)ws_size; (void)in_sizes; (void)n_in; (void)out_size;

  k_init <<<(n + 255) / 256, 256, 0, stream>>>(deg, counter, n);
  k_count<<<(E + 255) / 256, 256, 0, stream>>>(dstp, deg, E);
  k_alloc<<<(n + 255) / 256, 256, 0, stream>>>(deg, row_ptr, fillpos, colx, dinv, counter, n);
  k_fill <<<(E + 255) / 256, 256, 0, stream>>>(srcp, dstp, fillpos, colx, E);

  k_cast <<<6250, 256, 0, stream>>>((const float4*)x, (uint4*)Xb, n * 128 / 8);
  k_prepW<<<216, 256, 0, stream>>>(W1, W2, W3, W4, Wt, Wt4);

  const int gg = (n + 63) / 64, ga = (n + 3) / 4;
  // layer 1
  k_gemmb<<<gg, 256, 0, stream>>>(Xb, Wt, dinv, Hb, n);
  k_aggb <<<ga, 256, 0, stream>>>(Hb, colx, row_ptr, deg, dinv, b1, Xc, n);
  // layer 2
  k_gemmb<<<gg, 256, 0, stream>>>(Xc, Wt + 16384, dinv, Hb, n);
  k_aggb <<<ga, 256, 0, stream>>>(Hb, colx, row_ptr, deg, dinv, b2, Xc, n);
  // layer 3
  k_gemmb<<<gg, 256, 0, stream>>>(Xc, Wt + 32768, dinv, Hb, n);
  k_aggb <<<ga, 256, 0, stream>>>(Hb, colx, row_ptr, deg, dinv, b3, Xc, n);
  // layer 4 (bf16 H [n][40]) + fused bias/log_softmax
  k_gemm48<<<gg, 256, 0, stream>>>(Xc, Wt4, dinv, Hb, n);
  k_agg40_lsm<<<ga, 256, 0, stream>>>(Hb, colx, row_ptr, deg, dinv, b4, out, n);
}